// Round 11
// baseline (343.734 us; speedup 1.0000x reference)
//
#include <hip/hip_runtime.h>
#include <hip/hip_bf16.h>
#include <hip/hip_cooperative_groups.h>
namespace cg = cooperative_groups;

// Attention_6828998000803 on MI355X (gfx950) — single fused cooperative kernel
// H=W=64, C=128, HEADS=4, DIM_HEAD=32, HW=4096, SCALE=10, EPS=1e-8
// phase1 qkv GEMM -> grid.sync -> phase2 flash attn (linear softmax, LDS-shared
// K/V tiles, verbatim round-9 body) -> grid.sync -> phase3 out projection.

typedef float  f32x4 __attribute__((ext_vector_type(4)));
typedef short  s16x8 __attribute__((ext_vector_type(8)));
typedef unsigned short u16x4 __attribute__((ext_vector_type(4)));
typedef unsigned short u16;

__device__ __forceinline__ u16 f2bf(float f) {
  unsigned int u = __float_as_uint(f);
  u += 0x7FFFu + ((u >> 16) & 1u);   // round-to-nearest-even
  return (u16)(u >> 16);
}
__device__ __forceinline__ float bf2f(u16 u) {
  return __uint_as_float(((unsigned int)u) << 16);
}
__device__ __forceinline__ s16x8 load8f_bf16(const float* p) {
  const f32x4* q = (const f32x4*)p;
  f32x4 a = q[0], b = q[1];
  s16x8 r;
  r[0]=(short)f2bf(a[0]); r[1]=(short)f2bf(a[1]); r[2]=(short)f2bf(a[2]); r[3]=(short)f2bf(a[3]);
  r[4]=(short)f2bf(b[0]); r[5]=(short)f2bf(b[1]); r[6]=(short)f2bf(b[2]); r[7]=(short)f2bf(b[3]);
  return r;
}

// LDS map (bytes): [0,32K) Kbuf[2][256][64B]swz  (later comb[16][16][32]f32)
//                  [32K,64K) Vbuf[2][32][512B]swz
//                  [64K,96K) P[16 waves][16][128B]swz
//                  [96K..99456) dl[16][16]f32, scs[32]f32
__global__ __launch_bounds__(1024, 4) void fused_kernel(
    const float* __restrict__ x, const float* __restrict__ w_in,
    const float* __restrict__ w_out, const float* __restrict__ b_out,
    u16* __restrict__ Qb, u16* __restrict__ Kb, u16* __restrict__ Vtb,
    float* __restrict__ sq, float* __restrict__ Oat,
    float* __restrict__ denom, float* __restrict__ out) {
  __shared__ __align__(16) char lds[99456];
  const int tid = threadIdx.x;
  const int w = tid >> 6, lane = tid & 63, li = lane & 15, kg = lane >> 4;
  const int b = blockIdx.x;

  // ================= phase 1: qkv = x @ w_in^T ==========================
  // block b: x-rows b*16..+16, all 384 cols (24 col-tiles; wave w does
  // tiles {w, w+16<24}).  q,k -> bf16 [h][i][d] + sumsq atomics; v -> V^T.
  {
    const int r0 = b * 16;
    s16x8 ax[4];
#pragma unroll
    for (int kc = 0; kc < 4; ++kc)
      ax[kc] = load8f_bf16(x + (size_t)(r0 + li) * 128 + kc * 32 + kg * 8);
    for (int t = w; t < 24; t += 16) {
      const int c = t * 16 + li;
      f32x4 acc = {0.f, 0.f, 0.f, 0.f};
#pragma unroll
      for (int kc = 0; kc < 4; ++kc) {
        s16x8 bw = load8f_bf16(w_in + (size_t)c * 128 + kc * 32 + kg * 8);
        acc = __builtin_amdgcn_mfma_f32_16x16x32_bf16(ax[kc], bw, acc, 0, 0, 0);
      }
      const int g = c >> 7, colrel = c & 127;
      const int h2 = colrel >> 5, d = colrel & 31;
      const int rr = r0 + kg * 4;
      if (g == 2) {
        u16x4 pv;
#pragma unroll
        for (int r = 0; r < 4; ++r) pv[r] = f2bf(acc[r]);
        *(u16x4*)(Vtb + ((size_t)(h2 * 32 + d) * 4096 + rr)) = pv;  // V^T[h][d][i]
      } else {
        float ss = acc[0]*acc[0] + acc[1]*acc[1] + acc[2]*acc[2] + acc[3]*acc[3];
        ss += __shfl_xor(ss, 16);
        ss += __shfl_xor(ss, 32);          // sum over this tile's 16 rows
        u16* dst = (g == 0 ? Qb : Kb);
#pragma unroll
        for (int r = 0; r < 4; ++r)
          dst[((size_t)h2 * 4096 + rr + r) * 32 + d] = f2bf(acc[r]);
        if (lane < 16) atomicAdd(sq + g * 128 + colrel, ss);
      }
    }
  }
  __threadfence();
  cg::this_grid().sync();

  // ================= phase 2: flash attention ===========================
  // block b -> (q0 = (b&63)*64, h = b>>6), 16 waves = (wq 0..3) x (wk 0..3).
  {
    const int h = b >> 6, q0 = (b & 63) * 64;
    const int wq = w >> 2, wk = w & 3;
    float* dl  = (float*)(lds + 98304);
    float* scs = (float*)(lds + 99328);
    const u16* Kh = Kb  + (size_t)h * 4096 * 32;
    const u16* Vh = Vtb + (size_t)h * 32 * 4096;
    const int jl = tid >> 2, sl = tid & 3;     // K staging coords (16B granules)
    const int dv = tid >> 5, sv = tid & 31;    // V staging coords

    // stage tile 0 (keys [0,256))
    {
      s16x8 kreg = *(const s16x8*)(Kh + (size_t)jl * 32 + sl * 8);
      s16x8 vreg = *(const s16x8*)(Vh + (size_t)dv * 4096 + sv * 8);
      *(s16x8*)(lds + jl * 64 + ((sl * 16) ^ ((jl & 7) << 4))) = kreg;
      *(s16x8*)(lds + 32768 + dv * 512 + ((sv * 16) ^ ((dv & 7) << 4))) = vreg;
    }
    // scale table: 10/(||q_d|| * ||k_d||)  (wave 0, from global sq)
    if (w == 0) {
      const int kind = lane >> 5, d = lane & 31;
      float n = fmaxf(sqrtf(sq[kind * 128 + h * 32 + d]), 1e-8f);
      float other = __shfl_xor(n, 32);
      if (lane < 32) scs[lane] = 10.f / (n * other);
    }
    __syncthreads();

    // Q fragment (rows q0+wq*16+[0,16)), scale folded in
    s16x8 aq;
    {
      const u16* qp = Qb + ((size_t)h * 4096 + q0 + wq * 16 + li) * 32 + kg * 8;
      s16x8 qr = *(const s16x8*)qp;
#pragma unroll
      for (int e = 0; e < 8; ++e) aq[e] = (short)f2bf(bf2f((u16)qr[e]) * scs[kg * 8 + e]);
    }

    f32x4 acc0 = {0,0,0,0}, acc1 = {0,0,0,0};
    float sden = 0.f;
    const int psw  = (li & 7) << 4;
    char* Pslab = lds + 65536 + w * 2048 + li * 128;
    const int kswz = (kg * 16) ^ psw;

    int cur = 0;
    for (int jt = 0; jt < 16; ++jt) {
      // prefetch next tile into regs (lands during compute below)
      s16x8 kreg = {}, vreg = {};
      if (jt < 15) {
        const int j0n = (jt + 1) * 256;
        kreg = *(const s16x8*)(Kh + (size_t)(j0n + jl) * 32 + sl * 8);
        vreg = *(const s16x8*)(Vh + (size_t)dv * 4096 + j0n + sv * 8);
      }
      const char* Kc = lds + cur * 16384;
      const char* Vc = lds + 32768 + cur * 16384;
      // S^T = K Q^T over this wave's 64-key quarter: lane holds S[j][q=li]
      f32x4 st[4];
#pragma unroll
      for (int jb = 0; jb < 4; ++jb) {
        s16x8 kf = *(const s16x8*)(Kc + (wk * 64 + jb * 16 + li) * 64 + kswz);
        f32x4 z = {0, 0, 0, 0};
        st[jb] = __builtin_amdgcn_mfma_f32_16x16x32_bf16(kf, aq, z, 0, 0, 0);
      }
      // exp (no max), denom accumulate, pack P -> per-wave LDS slab
#pragma unroll
      for (int jb = 0; jb < 4; ++jb) {
        float p0 = __expf(st[jb][0]), p1 = __expf(st[jb][1]);
        float p2 = __expf(st[jb][2]), p3 = __expf(st[jb][3]);
        sden += (p0 + p1) + (p2 + p3);
        uint2 pk;
        pk.x = (unsigned)f2bf(p0) | ((unsigned)f2bf(p1) << 16);
        pk.y = (unsigned)f2bf(p2) | ((unsigned)f2bf(p3) << 16);
        *(uint2*)(Pslab + ((jb * 32 + kg * 8) ^ psw)) = pk;
      }
      // O += P V  (wave-internal P round-trip; V from shared staged tile)
#pragma unroll
      for (int c = 0; c < 2; ++c) {
        s16x8 ap = *(const s16x8*)(Pslab + ((c * 64 + kg * 16) ^ psw));
        const int vsw = ((wk * 8 + c * 4 + kg) * 16) ^ psw;
        s16x8 vf0 = *(const s16x8*)(Vc + li * 512 + vsw);
        s16x8 vf1 = *(const s16x8*)(Vc + (li + 16) * 512 + vsw);
        acc0 = __builtin_amdgcn_mfma_f32_16x16x32_bf16(ap, vf0, acc0, 0, 0, 0);
        acc1 = __builtin_amdgcn_mfma_f32_16x16x32_bf16(ap, vf1, acc1, 0, 0, 0);
      }
      __syncthreads();
      if (jt < 15) {
        char* Kn = lds + (cur ^ 1) * 16384;
        char* Vn = lds + 32768 + (cur ^ 1) * 16384;
        *(s16x8*)(Kn + jl * 64 + ((sl * 16) ^ ((jl & 7) << 4))) = kreg;
        *(s16x8*)(Vn + dv * 512 + ((sv * 16) ^ ((dv & 7) << 4))) = vreg;
      }
      __syncthreads();
      cur ^= 1;
    }

    // combine partials across wk via LDS (no atomics)
    sden += __shfl_xor(sden, 16);
    sden += __shfl_xor(sden, 32);
    if (lane < 16) dl[w * 16 + li] = sden;
    float* comb = (float*)lds;               // overlays Kbuf (done with it)
#pragma unroll
    for (int r = 0; r < 4; ++r) {
      comb[(w * 16 + kg * 4 + r) * 32 + li]      = acc0[r];
      comb[(w * 16 + kg * 4 + r) * 32 + 16 + li] = acc1[r];
    }
    __syncthreads();
    {
      const int row = tid >> 4, cp = (tid & 15) * 2;
      const int wb = (row >> 4) * 4, r16 = row & 15;
      float o0 = 0.f, o1 = 0.f;
#pragma unroll
      for (int k2 = 0; k2 < 4; ++k2) {
        const float* src = comb + ((wb + k2) * 16 + r16) * 32 + cp;
        o0 += src[0]; o1 += src[1];
      }
      float2 o2 = {o0, o1};
      *(float2*)(Oat + (size_t)(q0 + row) * 128 + h * 32 + cp) = o2;
      if (tid < 64) {
        float ds = 0.f;
#pragma unroll
        for (int k2 = 0; k2 < 4; ++k2) ds += dl[((tid >> 4) * 4 + k2) * 16 + (tid & 15)];
        denom[(size_t)h * 4096 + q0 + tid] = ds;
      }
    }
  }
  __threadfence();
  cg::this_grid().sync();

  // ================= phase 3: out = (Oat/denom) @ w_out^T + b_out =======
  // block b: rows b*16..+16; waves 0..7 each do one 16-col tile.
  if (w < 8) {
    const int i0 = b * 16;
    const int i = i0 + li;
    s16x8 ao[4];
#pragma unroll
    for (int kc = 0; kc < 4; ++kc) {
      const float inv = 1.f / denom[(size_t)kc * 4096 + i];
      const f32x4* p = (const f32x4*)(Oat + (size_t)i * 128 + kc * 32 + kg * 8);
      f32x4 a = p[0], bb = p[1];
      s16x8 r;
      r[0]=(short)f2bf(a[0]*inv);  r[1]=(short)f2bf(a[1]*inv);
      r[2]=(short)f2bf(a[2]*inv);  r[3]=(short)f2bf(a[3]*inv);
      r[4]=(short)f2bf(bb[0]*inv); r[5]=(short)f2bf(bb[1]*inv);
      r[6]=(short)f2bf(bb[2]*inv); r[7]=(short)f2bf(bb[3]*inv);
      ao[kc] = r;
    }
    const int c = w * 16 + li;
    f32x4 acc = {0, 0, 0, 0};
#pragma unroll
    for (int kc = 0; kc < 4; ++kc) {
      s16x8 bw = load8f_bf16(w_out + (size_t)c * 128 + kc * 32 + kg * 8);
      acc = __builtin_amdgcn_mfma_f32_16x16x32_bf16(ao[kc], bw, acc, 0, 0, 0);
    }
    const float bias = b_out[c];
#pragma unroll
    for (int r = 0; r < 4; ++r)
      out[(size_t)(i0 + kg * 4 + r) * 128 + c] = acc[r] + bias;
  }
}

// ---------------------------------------------------------------------------
extern "C" void kernel_launch(void* const* d_in, const int* in_sizes, int n_in,
                              void* d_out, int out_size, void* d_ws, size_t ws_size,
                              hipStream_t stream) {
  const float* x     = (const float*)d_in[0];
  const float* w_in  = (const float*)d_in[1];
  const float* w_out = (const float*)d_in[2];
  const float* b_out = (const float*)d_in[3];
  float* out = (float*)d_out;

  char* ws = (char*)d_ws;
  float* Oat   = (float*)ws;                            // [4096][128] f32 (2MB)
  float* denom = (float*)(ws + 2097152);                // [4][4096] f32 (64KB)
  float* sq    = (float*)(ws + 2097152 + 65536);        // [2][128] f32 sumsq (1KB)
  u16*   Qb  = (u16*)(ws + 2097152 + 65536 + 1024);                 // [4][4096][32]
  u16*   Kb  = (u16*)(ws + 2097152 + 65536 + 1024 + 1048576);       // [4][4096][32]
  u16*   Vtb = (u16*)(ws + 2097152 + 65536 + 1024 + 2 * 1048576);   // [4][32][4096]

  hipMemsetAsync(sq, 0, 1024, stream);   // sumsq accumulators
  void* args[] = {(void*)&x, (void*)&w_in, (void*)&w_out, (void*)&b_out,
                  (void*)&Qb, (void*)&Kb, (void*)&Vtb, (void*)&sq,
                  (void*)&Oat, (void*)&denom, (void*)&out};
  hipLaunchCooperativeKernel((const void*)fused_kernel, dim3(256), dim3(1024),
                             args, 0, stream);
}

// Round 12
// 103.498 us; speedup vs baseline: 3.3211x; 3.3211x over previous
//
#include <hip/hip_runtime.h>
#include <hip/hip_bf16.h>

// Attention_6828998000803 on MI355X (gfx950)
// H=W=64, C=128, HEADS=4, DIM_HEAD=32, HW=4096, SCALE=10, EPS=1e-8
//
// qkv GEMM (no sync, no atomics, writes Q,K,V^T bf16 + part_sq[col][mb])
// -> flash attention (linear softmax, LDS-shared K/V tiles double-buffered
//    with ONE barrier per tile, LDS partial combine, no atomics)
// -> output projection (divide by denom, bf16 MFMA, + bias)

typedef float  f32x4 __attribute__((ext_vector_type(4)));
typedef short  s16x8 __attribute__((ext_vector_type(8)));
typedef unsigned short u16x4 __attribute__((ext_vector_type(4)));
typedef unsigned short u16;

__device__ __forceinline__ u16 f2bf(float f) {
  unsigned int u = __float_as_uint(f);
  u += 0x7FFFu + ((u >> 16) & 1u);   // round-to-nearest-even
  return (u16)(u >> 16);
}
__device__ __forceinline__ float bf2f(u16 u) {
  return __uint_as_float(((unsigned int)u) << 16);
}
__device__ __forceinline__ s16x8 load8f_bf16(const float* p) {
  const f32x4* q = (const f32x4*)p;
  f32x4 a = q[0], b = q[1];
  s16x8 r;
  r[0]=(short)f2bf(a[0]); r[1]=(short)f2bf(a[1]); r[2]=(short)f2bf(a[2]); r[3]=(short)f2bf(a[3]);
  r[4]=(short)f2bf(b[0]); r[5]=(short)f2bf(b[1]); r[6]=(short)f2bf(b[2]); r[7]=(short)f2bf(b[3]);
  return r;
}

// ---------------------------------------------------------------------------
// K1: qkv = x @ w_in^T  (M=4096, K=128, N=384), grid (256 Mtiles of 16, 3 g)
// 4 waves: wave w owns cols w*32..+32 of its group (disjoint -> B loaded once
// per block).  q,k -> bf16 [h][i][d] + part_sq[g*128+col][mb] direct store;
// v -> bf16 V^T[h][d][i].  No LDS, no syncthreads, no atomics.
// ---------------------------------------------------------------------------
__global__ __launch_bounds__(256) void qkv_kernel(
    const float* __restrict__ x, const float* __restrict__ w_in,
    u16* __restrict__ Qb, u16* __restrict__ Kb, u16* __restrict__ Vtb,
    float* __restrict__ part_sq) {
  const int tid = threadIdx.x;
  const int w = tid >> 6, lane = tid & 63, li = lane & 15, kg = lane >> 4;
  const int g = blockIdx.y;
  const int mb = blockIdx.x;
  const int r0 = mb * 16;

  s16x8 ax[4];
#pragma unroll
  for (int kc = 0; kc < 4; ++kc)
    ax[kc] = load8f_bf16(x + (size_t)(r0 + li) * 128 + kc * 32 + kg * 8);

#pragma unroll
  for (int nt = 0; nt < 2; ++nt) {
    const int colrel = w * 32 + nt * 16 + li;
    f32x4 acc = {0.f, 0.f, 0.f, 0.f};
#pragma unroll
    for (int kc = 0; kc < 4; ++kc) {
      s16x8 bw = load8f_bf16(w_in + ((size_t)g * 128 + colrel) * 128 + kc * 32 + kg * 8);
      acc = __builtin_amdgcn_mfma_f32_16x16x32_bf16(ax[kc], bw, acc, 0, 0, 0);
    }
    const int h = colrel >> 5, d = colrel & 31;
    const int rr = r0 + kg * 4;
    if (g == 2) {
      u16x4 pv;
#pragma unroll
      for (int r = 0; r < 4; ++r) pv[r] = f2bf(acc[r]);
      *(u16x4*)(Vtb + ((size_t)(h * 32 + d) * 4096 + rr)) = pv;   // V^T[h][d][i]
    } else {
      float ss = acc[0]*acc[0] + acc[1]*acc[1] + acc[2]*acc[2] + acc[3]*acc[3];
      ss += __shfl_xor(ss, 16);
      ss += __shfl_xor(ss, 32);            // sum over the tile's 16 rows
      u16* dst = (g == 0 ? Qb : Kb);
#pragma unroll
      for (int r = 0; r < 4; ++r)
        dst[((size_t)h * 4096 + rr + r) * 32 + d] = f2bf(acc[r]);
      if (lane < 16)
        part_sq[((size_t)g * 128 + w * 32 + nt * 16 + lane) * 256 + mb] = ss;
    }
  }
}

// ---------------------------------------------------------------------------
// K2: flash attention, linear softmax.  grid (64 q-blocks, 4 heads) = 256
// blocks (1/CU), 1024 thr = 16 waves = (wq 0..3) x (wk 0..3).
// Wave (wq,wk): q-rows q0+wq*16+[0,16) x keys (per 256-key staged tile)
// wk*64+[0,64).  K/V double-buffered in swizzled LDS, staged once per tile,
// ONE barrier per tile (write target = other buffer, protected by previous
// iteration's barrier).  LDS partial combine; plain stores, no atomics.
// LDS map (bytes): [0,32K) Kbuf[2][256][64B]swz (later comb[16][16][32]f32)
//                  [32K,64K) Vbuf[2][32][512B]swz
//                  [64K,96K) P[16 waves][16][128B]swz
//                  [96K..99456) dl[16][16]f32, scs[32]f32
// ---------------------------------------------------------------------------
__global__ __launch_bounds__(1024, 4) void attn_kernel(
    const u16* __restrict__ Qb, const u16* __restrict__ Kb,
    const u16* __restrict__ Vtb, const float* __restrict__ part_sq,
    float* __restrict__ Oat, float* __restrict__ denom) {
  __shared__ __align__(16) char lds[99456];
  const int tid = threadIdx.x;
  const int w = tid >> 6, lane = tid & 63, li = lane & 15, kg = lane >> 4;
  const int wq = w >> 2, wk = w & 3;
  const int h = blockIdx.y, q0 = blockIdx.x * 64;
  float* dl  = (float*)(lds + 98304);
  float* scs = (float*)(lds + 99328);
  const u16* Kh = Kb  + (size_t)h * 4096 * 32;
  const u16* Vh = Vtb + (size_t)h * 32 * 4096;
  const int jl = tid >> 2, sl = tid & 3;     // K staging coords (16B granules)
  const int dv = tid >> 5, sv = tid & 31;    // V staging coords

  // ---- stage tile 0 (keys [0,256))
  {
    s16x8 kreg = *(const s16x8*)(Kh + (size_t)jl * 32 + sl * 8);
    s16x8 vreg = *(const s16x8*)(Vh + (size_t)dv * 4096 + sv * 8);
    *(s16x8*)(lds + jl * 64 + ((sl * 16) ^ ((jl & 7) << 4))) = kreg;
    *(s16x8*)(lds + 32768 + dv * 512 + ((sv * 16) ^ ((dv & 7) << 4))) = vreg;
  }
  // ---- scale table (wave 0): 10/(||q_d|| * ||k_d||)
  if (w == 0) {
    const int kind = lane >> 5, d = lane & 31;
    const f32x4* p4 = (const f32x4*)(part_sq + (size_t)(kind * 128 + h * 32 + d) * 256);
    float sum = 0.f;
#pragma unroll
    for (int m = 0; m < 64; ++m) { f32x4 v = p4[m]; sum += (v[0]+v[1]) + (v[2]+v[3]); }
    float n = fmaxf(sqrtf(sum), 1e-8f);
    float other = __shfl_xor(n, 32);
    if (lane < 32) scs[lane] = 10.f / (n * other);
  }
  __syncthreads();

  // ---- Q fragment (rows q0+wq*16+[0,16)), scale folded in
  s16x8 aq;
  {
    const u16* qp = Qb + ((size_t)h * 4096 + q0 + wq * 16 + li) * 32 + kg * 8;
    s16x8 qr = *(const s16x8*)qp;
#pragma unroll
    for (int e = 0; e < 8; ++e) aq[e] = (short)f2bf(bf2f((u16)qr[e]) * scs[kg * 8 + e]);
  }

  f32x4 acc0 = {0,0,0,0}, acc1 = {0,0,0,0};
  float sden = 0.f;
  const int psw  = (li & 7) << 4;
  char* Pslab = lds + 65536 + w * 2048 + li * 128;
  const int kswz = (kg * 16) ^ psw;

  int cur = 0;
  for (int jt = 0; jt < 16; ++jt) {
    // prefetch next tile into regs (lands during compute below)
    s16x8 kreg = {}, vreg = {};
    if (jt < 15) {
      const int j0n = (jt + 1) * 256;
      kreg = *(const s16x8*)(Kh + (size_t)(j0n + jl) * 32 + sl * 8);
      vreg = *(const s16x8*)(Vh + (size_t)dv * 4096 + j0n + sv * 8);
    }
    const char* Kc = lds + cur * 16384;
    const char* Vc = lds + 32768 + cur * 16384;
    // S^T = K Q^T over this wave's 64-key quarter: lane holds S[j][q=li]
    f32x4 st[4];
#pragma unroll
    for (int jb = 0; jb < 4; ++jb) {
      s16x8 kf = *(const s16x8*)(Kc + (wk * 64 + jb * 16 + li) * 64 + kswz);
      f32x4 z = {0, 0, 0, 0};
      st[jb] = __builtin_amdgcn_mfma_f32_16x16x32_bf16(kf, aq, z, 0, 0, 0);
    }
    // exp (no max), denom accumulate, pack P -> per-wave LDS slab
#pragma unroll
    for (int jb = 0; jb < 4; ++jb) {
      float p0 = __expf(st[jb][0]), p1 = __expf(st[jb][1]);
      float p2 = __expf(st[jb][2]), p3 = __expf(st[jb][3]);
      sden += (p0 + p1) + (p2 + p3);
      uint2 pk;
      pk.x = (unsigned)f2bf(p0) | ((unsigned)f2bf(p1) << 16);
      pk.y = (unsigned)f2bf(p2) | ((unsigned)f2bf(p3) << 16);
      *(uint2*)(Pslab + ((jb * 32 + kg * 8) ^ psw)) = pk;
    }
    // O += P V  (wave-internal P round-trip; V from shared staged tile)
#pragma unroll
    for (int c = 0; c < 2; ++c) {
      s16x8 ap = *(const s16x8*)(Pslab + ((c * 64 + kg * 16) ^ psw));
      const int vsw = ((wk * 8 + c * 4 + kg) * 16) ^ psw;
      s16x8 vf0 = *(const s16x8*)(Vc + li * 512 + vsw);
      s16x8 vf1 = *(const s16x8*)(Vc + (li + 16) * 512 + vsw);
      acc0 = __builtin_amdgcn_mfma_f32_16x16x32_bf16(ap, vf0, acc0, 0, 0, 0);
      acc1 = __builtin_amdgcn_mfma_f32_16x16x32_bf16(ap, vf1, acc1, 0, 0, 0);
    }
    // stage next tile into the OTHER buffer (its readers finished at the
    // barrier that ended iteration jt-1), then ONE barrier
    if (jt < 15) {
      char* Kn = lds + (cur ^ 1) * 16384;
      char* Vn = lds + 32768 + (cur ^ 1) * 16384;
      *(s16x8*)(Kn + jl * 64 + ((sl * 16) ^ ((jl & 7) << 4))) = kreg;
      *(s16x8*)(Vn + dv * 512 + ((sv * 16) ^ ((dv & 7) << 4))) = vreg;
    }
    __syncthreads();
    cur ^= 1;
  }

  // ---- combine partials across wk via LDS (no atomics)
  sden += __shfl_xor(sden, 16);
  sden += __shfl_xor(sden, 32);
  if (lane < 16) dl[w * 16 + li] = sden;
  float* comb = (float*)lds;               // overlays Kbuf (done with it)
#pragma unroll
  for (int r = 0; r < 4; ++r) {
    comb[(w * 16 + kg * 4 + r) * 32 + li]      = acc0[r];
    comb[(w * 16 + kg * 4 + r) * 32 + 16 + li] = acc1[r];
  }
  __syncthreads();
  {
    const int row = tid >> 4, cp = (tid & 15) * 2;
    const int wb = (row >> 4) * 4, r16 = row & 15;
    float o0 = 0.f, o1 = 0.f;
#pragma unroll
    for (int k2 = 0; k2 < 4; ++k2) {
      const float* src = comb + ((wb + k2) * 16 + r16) * 32 + cp;
      o0 += src[0]; o1 += src[1];
    }
    float2 o2 = {o0, o1};
    *(float2*)(Oat + (size_t)(q0 + row) * 128 + h * 32 + cp) = o2;
    if (tid < 64) {
      float ds = 0.f;
#pragma unroll
      for (int k2 = 0; k2 < 4; ++k2) ds += dl[((tid >> 4) * 4 + k2) * 16 + (tid & 15)];
      denom[(size_t)h * 4096 + q0 + tid] = ds;
    }
  }
}

// ---------------------------------------------------------------------------
// K3: out = (Oat/denom) @ w_out^T + b_out  (M=4096, K=128, N=128)
// grid (256 Mtiles of 16, 2 N-halves), 256 thr = 4 waves.
// ---------------------------------------------------------------------------
__global__ __launch_bounds__(256) void proj_kernel(
    const float* __restrict__ Oat, const float* __restrict__ denom,
    const float* __restrict__ w_out, const float* __restrict__ b_out,
    float* __restrict__ out) {
  const int tid = threadIdx.x;
  const int w = tid >> 6, lane = tid & 63, li = lane & 15, kg = lane >> 4;
  const int i0 = blockIdx.x * 16;
  const int n0 = blockIdx.y * 64;
  const int i = i0 + li;

  s16x8 ao[4];
#pragma unroll
  for (int kc = 0; kc < 4; ++kc) {
    const float inv = 1.f / denom[(size_t)kc * 4096 + i];
    const f32x4* p = (const f32x4*)(Oat + (size_t)i * 128 + kc * 32 + kg * 8);
    f32x4 a = p[0], b = p[1];
    s16x8 r;
    r[0]=(short)f2bf(a[0]*inv); r[1]=(short)f2bf(a[1]*inv);
    r[2]=(short)f2bf(a[2]*inv); r[3]=(short)f2bf(a[3]*inv);
    r[4]=(short)f2bf(b[0]*inv); r[5]=(short)f2bf(b[1]*inv);
    r[6]=(short)f2bf(b[2]*inv); r[7]=(short)f2bf(b[3]*inv);
    ao[kc] = r;
  }
  const int c = n0 + w * 16 + li;
  f32x4 acc = {0, 0, 0, 0};
#pragma unroll
  for (int kc = 0; kc < 4; ++kc) {
    s16x8 bw = load8f_bf16(w_out + (size_t)c * 128 + kc * 32 + kg * 8);
    acc = __builtin_amdgcn_mfma_f32_16x16x32_bf16(ao[kc], bw, acc, 0, 0, 0);
  }
  const float bias = b_out[c];
#pragma unroll
  for (int r = 0; r < 4; ++r)
    out[(size_t)(i0 + kg * 4 + r) * 128 + c] = acc[r] + bias;
}

// ---------------------------------------------------------------------------
extern "C" void kernel_launch(void* const* d_in, const int* in_sizes, int n_in,
                              void* d_out, int out_size, void* d_ws, size_t ws_size,
                              hipStream_t stream) {
  const float* x     = (const float*)d_in[0];
  const float* w_in  = (const float*)d_in[1];
  const float* w_out = (const float*)d_in[2];
  const float* b_out = (const float*)d_in[3];
  float* out = (float*)d_out;

  char* ws = (char*)d_ws;
  float* Oat     = (float*)ws;                          // [4096][128] f32 (2MB)
  float* denom   = (float*)(ws + 2097152);              // [4][4096] f32 (64KB)
  float* part_sq = (float*)(ws + 2097152 + 65536);      // [256][256] f32 (256KB)
  u16*   Qb  = (u16*)(ws + 2097152 + 65536 + 262144);               // [4][4096][32]
  u16*   Kb  = (u16*)(ws + 2097152 + 65536 + 262144 + 1048576);     // [4][4096][32]
  u16*   Vtb = (u16*)(ws + 2097152 + 65536 + 262144 + 2 * 1048576); // [4][32][4096]

  qkv_kernel <<<dim3(256, 3), 256,  0, stream>>>(x, w_in, Qb, Kb, Vtb, part_sq);
  attn_kernel<<<dim3(64, 4),  1024, 0, stream>>>(Qb, Kb, Vtb, part_sq, Oat, denom);
  proj_kernel<<<dim3(256, 2), 256,  0, stream>>>(Oat, denom, w_out, b_out, out);
}